// Round 11
// baseline (259.631 us; speedup 1.0000x reference)
//
#include <hip/hip_runtime.h>

// UpCaps fused, transposed lanes + packed-fp32, 2 px/wave for the 64-VGPR
// occupancy bucket (8 waves/EU). lane = a*8 + cg (cg = c/2); each lane holds
// votes for all 8 batches of its (a, 2cg..2cg+1) as v2f -> v_pk_fma_f32.
// MI355X VGPR buckets (m69): <=64 -> 8 waves/EU, <=128 -> 4. R8 (4px, 84 VGPR)
// sat in the 128 bucket at VALUBusy 52% (latency-bound). Here acc is 32 VGPR
// (2px), column-streamed conv keeps peak live ~55 -> force the 64 bucket with
// __launch_bounds__(512,8) for 2x latency hiding. R7/R10 lesson: cap < live
// spills catastrophically -- go/no-go check is VGPR<=64 AND WRITE ~18.4MB.
// x repacked into d_ws as xp[ci][iy][ixp][b] (padded): conv x-reads are
// wave-uniform 32B loads, no edge branches. Softmax over b lane-local; squash
// over a-lanes (xor 8,16,32); logit update over cg-lanes (xor 1,2,4).
// Output via 8KB LDS transpose -> full-64B-line stores.
// Shapes: x(8,16,96,96), w(5,5,16,8,16), out(8,16,192,192).
typedef float v2f __attribute__((ext_vector_type(2)));

#define XH 96
#define XW 96
#define CIN 16
#define NA 8
#define NC 16
#define OH 192
#define OW 192
#define WP 102                        // padded width: ix in [-1,100] -> ixp 0..101
#define PADN (CIN * XH * WP * 8)      // 1,253,376 floats

__global__ __launch_bounds__(256) void pad_x(const float* __restrict__ x,
                                             float* __restrict__ xp) {
  int idx = blockIdx.x * 256 + threadIdx.x;
  if (idx >= PADN) return;
  int b   = idx & 7;
  int t   = idx >> 3;
  int ixp = t % WP;
  int t2  = t / WP;
  int iy  = t2 % XH;
  int ci  = t2 / XH;
  int ix  = ixp - 1;
  float v = 0.f;
  if (ix >= 0 && ix < XW)
    v = x[((b * CIN + ci) * XH + iy) * XW + ix];
  xp[idx] = v;
}

// routes two pixels interleaved; va/vb = votes[b] (c-pair) for this lane's
// (a, 2cg..2cg+1). On exit qa/qb hold final squashed preds (c-pair).
__device__ __forceinline__ void route_pair(
    const v2f (&va)[8], const v2f (&vb)[8], int R, v2f& qa, v2f& qb)
{
  float lga[8], lgb[8];
#pragma unroll
  for (int b = 0; b < 8; ++b) { lga[b] = 0.f; lgb[b] = 0.f; }
#pragma unroll 1
  for (int r = 0; r < R; ++r) {
    float sla[8], slb[8];
    if (r == 0) {
#pragma unroll
      for (int b = 0; b < 8; ++b) { sla[b] = 0.125f; slb[b] = 0.125f; }
    } else {
      // softmax over batch: fully lane-local (lg dies into sl element-wise)
      float ma = lga[0], mb = lgb[0];
#pragma unroll
      for (int b = 1; b < 8; ++b) { ma = fmaxf(ma, lga[b]); mb = fmaxf(mb, lgb[b]); }
      float sa = 0.f, sb = 0.f;
#pragma unroll
      for (int b = 0; b < 8; ++b) {
        sla[b] = __expf(lga[b] - ma); sa += sla[b];
        slb[b] = __expf(lgb[b] - mb); sb += slb[b];
      }
      const float ira = __builtin_amdgcn_rcpf(sa);   // sa >= 1 > 0
      const float irb = __builtin_amdgcn_rcpf(sb);
#pragma unroll
      for (int b = 0; b < 8; ++b) { sla[b] *= ira; slb[b] *= irb; }
    }

    // preds = sum_b votes * sl : lane-local pk-FMA chain
    qa = (v2f){0.f, 0.f};  qb = (v2f){0.f, 0.f};
#pragma unroll
    for (int b = 0; b < 8; ++b) {
      qa = __builtin_elementwise_fma((v2f){sla[b], sla[b]}, va[b], qa);
      qb = __builtin_elementwise_fma((v2f){slb[b], slb[b]}, vb[b], qb);
    }

    // squash: norm^2 over atoms = reduce over a-lanes (bits 3..5)
    {
      float na0 = qa.x * qa.x, na1 = qa.y * qa.y;
      float nb0 = qb.x * qb.x, nb1 = qb.y * qb.y;
      na0 += __shfl_xor(na0, 8);  na1 += __shfl_xor(na1, 8);
      nb0 += __shfl_xor(nb0, 8);  nb1 += __shfl_xor(nb1, 8);
      na0 += __shfl_xor(na0, 16); na1 += __shfl_xor(na1, 16);
      nb0 += __shfl_xor(nb0, 16); nb1 += __shfl_xor(nb1, 16);
      na0 += __shfl_xor(na0, 32); na1 += __shfl_xor(na1, 32);
      nb0 += __shfl_xor(nb0, 32); nb1 += __shfl_xor(nb1, 32);
      qa.x *= sqrtf(na0) * __builtin_amdgcn_rcpf(1.f + na0);  // sqrt(n)/(1+n)
      qa.y *= sqrtf(na1) * __builtin_amdgcn_rcpf(1.f + na1);
      qb.x *= sqrtf(nb0) * __builtin_amdgcn_rcpf(1.f + nb0);
      qb.y *= sqrtf(nb1) * __builtin_amdgcn_rcpf(1.f + nb1);
    }

    // logits = softmaxed + sum_c votes*preds (reduce over cg-lanes, bits 0..2)
    if (r + 1 < R) {
#pragma unroll
      for (int b = 0; b < 8; ++b) {
        float da = fmaf(va[b].x, qa.x, va[b].y * qa.y);
        float db = fmaf(vb[b].x, qb.x, vb[b].y * qb.y);
        da += __shfl_xor(da, 1);  db += __shfl_xor(db, 1);
        da += __shfl_xor(da, 2);  db += __shfl_xor(db, 2);
        da += __shfl_xor(da, 4);  db += __shfl_xor(db, 4);
        lga[b] = sla[b] + da;     lgb[b] = slb[b] + db;
      }
    }
  }
}

__global__ __launch_bounds__(512, 8) void upcaps_tr6(
    const float* __restrict__ xp,    // padded [ci][iy][ixp][b]
    const float* __restrict__ wts,
    const int* __restrict__ nroutes,
    float* __restrict__ out)
{
  __shared__ float lds_out[16 * 128];   // 8KB: [pxi][a*16+c]

  const int lane = threadIdx.x & 63;
  const int wid  = threadIdx.x >> 6;    // 8 waves
  const int tile = blockIdx.x;          // 2304 blocks, 16 px each
  const int oy   = tile / 12;
  const int xg   = (tile - oy * 12) * 16;            // 64B-line aligned
  const int e    = wid & 1;                          // parity
  const int pxb  = e + ((wid >> 1) << 2);            // wave px: pxb, pxb+2
  const int oxw  = xg + pxb;
  const int a    = lane >> 3;
  const int cg   = lane & 7;
  // cols: ix = ixb + t + j, t in [0,2], j in [0,1] -> 4 cols
  const int ixp0 = __builtin_amdgcn_readfirstlane(((oxw - 2 + e) >> 1) + 1);
  const bool use_t2 = (e == 0);                      // wave-uniform
  const int wlane = a * NC + cg * 2;    // per-lane float offset into w[..][a][c]

  v2f acc[2][8];
#pragma unroll
  for (int j = 0; j < 2; ++j)
#pragma unroll
    for (int b = 0; b < 8; ++b) acc[j][b] = (v2f){0.f, 0.f};

  for (int ky = 0; ky < 5; ++ky) {
    const int py = oy - 2 + ky;
    if (py < 0 || py > 2 * XH - 2 || (py & 1)) continue;   // wave-uniform
    const int iy = py >> 1;
    const float* wk = wts + (ky * 5 + e) * (CIN * NA * NC) + wlane;
#pragma unroll 2
    for (int ci = 0; ci < CIN; ++ci) {
      const float* xrow = xp + ((ci * XH + iy) * WP + ixp0) * 8;  // uniform
      const v2f cw0 = *(const v2f*)(wk + ci * (NA * NC));
      const v2f cw1 = *(const v2f*)(wk + 2 * (CIN * NA * NC) + ci * (NA * NC));
      v2f cw2 = (v2f){0.f, 0.f};
      if (use_t2) cw2 = *(const v2f*)(wk + 4 * (CIN * NA * NC) + ci * (NA * NC));
      // column-streaming: col k feeds (tap t, px j) with t + j == k
#pragma unroll
      for (int k = 0; k < 4; ++k) {
        if (k == 3 && !use_t2) continue;           // odd parity: cols 0..2
        const float4 xlo = *(const float4*)(xrow + k * 8);      // uniform
        const float4 xhi = *(const float4*)(xrow + k * 8 + 4);
        const float xv[8] = {xlo.x, xlo.y, xlo.z, xlo.w,
                             xhi.x, xhi.y, xhi.z, xhi.w};
        if (k <= 1) {                              // t=k,   px0 (j=0)
#pragma unroll
          for (int b = 0; b < 8; ++b) {
            const v2f xs = (v2f){xv[b], xv[b]};
            acc[0][b] = __builtin_elementwise_fma(xs, (k == 0) ? cw0 : cw1, acc[0][b]);
          }
        }
        if (k >= 1 && k <= 2) {                    // t=k-1, px1 (j=1)
#pragma unroll
          for (int b = 0; b < 8; ++b) {
            const v2f xs = (v2f){xv[b], xv[b]};
            acc[1][b] = __builtin_elementwise_fma(xs, (k == 1) ? cw0 : cw1, acc[1][b]);
          }
        }
        if (k == 2 && use_t2) {                    // t=2,   px0
#pragma unroll
          for (int b = 0; b < 8; ++b) {
            const v2f xs = (v2f){xv[b], xv[b]};
            acc[0][b] = __builtin_elementwise_fma(xs, cw2, acc[0][b]);
          }
        }
        if (k == 3) {                              // t=2,   px1 (even only)
#pragma unroll
          for (int b = 0; b < 8; ++b) {
            const v2f xs = (v2f){xv[b], xv[b]};
            acc[1][b] = __builtin_elementwise_fma(xs, cw2, acc[1][b]);
          }
        }
      }
    }
  }

  // -------- routing (one interleaved pair) --------
  const int R = nroutes[0];
  v2f q0, q1;
  route_pair(acc[0], acc[1], R, q0, q1);

  // -------- stage results to LDS: [pxi][a*16+c] --------
  const int lbase = a * NC + cg * 2;
  *(v2f*)&lds_out[(pxb    ) * 128 + lbase] = q0;
  *(v2f*)&lds_out[(pxb + 2) * 128 + lbase] = q1;
  __syncthreads();

  // -------- coalesced output: thread -> (row r = a*16+c, quarter q) --------
  const int t = threadIdx.x;            // 512 threads: 128 rows x 4 quarters
  const int r = t >> 2, q = t & 3;
  float4 f;
  f.x = lds_out[(q * 4 + 0) * 128 + r];
  f.y = lds_out[(q * 4 + 1) * 128 + r];
  f.z = lds_out[(q * 4 + 2) * 128 + r];
  f.w = lds_out[(q * 4 + 3) * 128 + r];
  *(float4*)(out + r * (OH * OW) + oy * OW + xg + q * 4) = f;
}

extern "C" void kernel_launch(void* const* d_in, const int* in_sizes, int n_in,
                              void* d_out, int out_size, void* d_ws, size_t ws_size,
                              hipStream_t stream) {
  const float* x   = (const float*)d_in[0];
  const float* w   = (const float*)d_in[1];
  const int*   nr  = (const int*)d_in[2];
  float*       out = (float*)d_out;
  float*       xp  = (float*)d_ws;       // needs PADN*4 = 5,013,504 bytes

  pad_x<<<(PADN + 255) / 256, 256, 0, stream>>>(x, xp);
  upcaps_tr6<<<(OH * OW) / 16, 512, 0, stream>>>(xp, w, nr, out);
}

// Round 12
// 146.319 us; speedup vs baseline: 1.7744x; 1.7744x over previous
//
#include <hip/hip_runtime.h>

// UpCaps fused, transposed lanes + packed-fp32 math (R8 structure, (256,4)).
// lane = a*8 + cg (cg = c/2); each lane holds votes for all 8 batches of its
// (a, c=2cg..2cg+1) as float2 (v2f) -> conv inner loop is v_pk_fma_f32.
// x repacked into d_ws as xp[ci][iy][ixp][b] (padded) so conv x-reads are
// wave-uniform 32B loads, no edge branches. Softmax over b lane-local;
// squash reduces over a-lanes (xor 8,16,32); logit update over cg-lanes
// (xor 1,2,4). Output via 8KB LDS transpose -> full-64B-line stores.
// OCCUPANCY LEDGER (measured): kernel truly needs ~84 VGPR.
//   (256,3) cap 168: 84 VGPR, clean, 144us, occ 27%  <- R8
//   (256,4) cap 128: >= 84 -> codegen UNCHANGED, 4 blocks/CU (this round)
//   (256,5)/(512,8): force <=64-VGPR hw bucket < live -> ~0.5-1GB spill (R10/R11)
// gfx950 VGPR buckets (m69): waves/EU steps at 64/128/256 -> 4 waves/EU is the
// max for this kernel; do NOT request more.
// Shapes: x(8,16,96,96), w(5,5,16,8,16), out(8,16,192,192).
typedef float v2f __attribute__((ext_vector_type(2)));

#define XH 96
#define XW 96
#define CIN 16
#define NA 8
#define NC 16
#define OH 192
#define OW 192
#define WP 102                        // padded width: ix in [-1,100] -> ixp 0..101
#define PADN (CIN * XH * WP * 8)      // 1,253,376 floats

__global__ __launch_bounds__(256) void pad_x(const float* __restrict__ x,
                                             float* __restrict__ xp) {
  int idx = blockIdx.x * 256 + threadIdx.x;
  if (idx >= PADN) return;
  int b   = idx & 7;
  int t   = idx >> 3;
  int ixp = t % WP;
  int t2  = t / WP;
  int iy  = t2 % XH;
  int ci  = t2 / XH;
  int ix  = ixp - 1;
  float v = 0.f;
  if (ix >= 0 && ix < XW)
    v = x[((b * CIN + ci) * XH + iy) * XW + ix];
  xp[idx] = v;
}

// routes two pixels interleaved; va/vb = votes[b] (c-pair) for this lane's
// (a, 2cg..2cg+1). On exit qa/qb hold final squashed preds (c-pair).
__device__ __forceinline__ void route_pair(
    const v2f (&va)[8], const v2f (&vb)[8], int R, v2f& qa, v2f& qb)
{
  float lga[8], lgb[8];
#pragma unroll
  for (int b = 0; b < 8; ++b) { lga[b] = 0.f; lgb[b] = 0.f; }
#pragma unroll 1
  for (int r = 0; r < R; ++r) {
    float sla[8], slb[8];
    if (r == 0) {
#pragma unroll
      for (int b = 0; b < 8; ++b) { sla[b] = 0.125f; slb[b] = 0.125f; }
    } else {
      // softmax over batch: fully lane-local
      float ma = lga[0], mb = lgb[0];
#pragma unroll
      for (int b = 1; b < 8; ++b) { ma = fmaxf(ma, lga[b]); mb = fmaxf(mb, lgb[b]); }
      float sa = 0.f, sb = 0.f;
#pragma unroll
      for (int b = 0; b < 8; ++b) {
        sla[b] = __expf(lga[b] - ma); sa += sla[b];
        slb[b] = __expf(lgb[b] - mb); sb += slb[b];
      }
      const float ira = __builtin_amdgcn_rcpf(sa);   // sa >= 1 > 0
      const float irb = __builtin_amdgcn_rcpf(sb);
#pragma unroll
      for (int b = 0; b < 8; ++b) { sla[b] *= ira; slb[b] *= irb; }
    }

    // preds = sum_b votes * sl : lane-local pk-FMA chain
    qa = (v2f){0.f, 0.f};  qb = (v2f){0.f, 0.f};
#pragma unroll
    for (int b = 0; b < 8; ++b) {
      qa = __builtin_elementwise_fma((v2f){sla[b], sla[b]}, va[b], qa);
      qb = __builtin_elementwise_fma((v2f){slb[b], slb[b]}, vb[b], qb);
    }

    // squash: norm^2 over atoms = reduce over a-lanes (bits 3..5)
    {
      float na0 = qa.x * qa.x, na1 = qa.y * qa.y;
      float nb0 = qb.x * qb.x, nb1 = qb.y * qb.y;
      na0 += __shfl_xor(na0, 8);  na1 += __shfl_xor(na1, 8);
      nb0 += __shfl_xor(nb0, 8);  nb1 += __shfl_xor(nb1, 8);
      na0 += __shfl_xor(na0, 16); na1 += __shfl_xor(na1, 16);
      nb0 += __shfl_xor(nb0, 16); nb1 += __shfl_xor(nb1, 16);
      na0 += __shfl_xor(na0, 32); na1 += __shfl_xor(na1, 32);
      nb0 += __shfl_xor(nb0, 32); nb1 += __shfl_xor(nb1, 32);
      qa.x *= sqrtf(na0) * __builtin_amdgcn_rcpf(1.f + na0);  // sqrt(n)/(1+n)
      qa.y *= sqrtf(na1) * __builtin_amdgcn_rcpf(1.f + na1);
      qb.x *= sqrtf(nb0) * __builtin_amdgcn_rcpf(1.f + nb0);
      qb.y *= sqrtf(nb1) * __builtin_amdgcn_rcpf(1.f + nb1);
    }

    // logits = softmaxed + sum_c votes*preds (reduce over cg-lanes, bits 0..2)
    if (r + 1 < R) {
#pragma unroll
      for (int b = 0; b < 8; ++b) {
        float da = fmaf(va[b].x, qa.x, va[b].y * qa.y);
        float db = fmaf(vb[b].x, qb.x, vb[b].y * qb.y);
        da += __shfl_xor(da, 1);  db += __shfl_xor(db, 1);
        da += __shfl_xor(da, 2);  db += __shfl_xor(db, 2);
        da += __shfl_xor(da, 4);  db += __shfl_xor(db, 4);
        lga[b] = sla[b] + da;     lgb[b] = slb[b] + db;
      }
    }
  }
}

__global__ __launch_bounds__(256, 4) void upcaps_tr7(
    const float* __restrict__ xp,    // padded [ci][iy][ixp][b]
    const float* __restrict__ wts,
    const int* __restrict__ nroutes,
    float* __restrict__ out)
{
  __shared__ float lds_out[16 * 128];   // 8KB: [pxi][a*16+c]

  const int lane = threadIdx.x & 63;
  const int wid  = threadIdx.x >> 6;
  const int tile = blockIdx.x;          // 2304 blocks, 16 px each
  const int oy   = tile / 12;
  const int xg   = (tile - oy * 12) * 16;            // 64B-line aligned
  const int pxb  = (wid & 1) + ((wid >> 1) << 3);    // wave px: pxb + 2j
  const int oxw  = xg + pxb;
  const int a    = lane >> 3;
  const int cg   = lane & 7;
  const int e    = oxw & 1;
  // conv input col: ix = ixb + t + j,  t,j in [0,2]x[0,3]
  const int ixp0 = __builtin_amdgcn_readfirstlane(((oxw - 2 + e) >> 1) + 1);
  const bool use_t2 = (__builtin_amdgcn_readfirstlane(e) == 0);
  const int wlane = a * NC + cg * 2;    // per-lane float offset into w[..][a][c]

  v2f acc[4][8];
#pragma unroll
  for (int j = 0; j < 4; ++j)
#pragma unroll
    for (int b = 0; b < 8; ++b) acc[j][b] = (v2f){0.f, 0.f};

  for (int ky = 0; ky < 5; ++ky) {
    const int py = oy - 2 + ky;
    if (py < 0 || py > 2 * XH - 2 || (py & 1)) continue;   // wave-uniform
    const int iy = py >> 1;
    const float* wk = wts + (ky * 5 + e) * (CIN * NA * NC) + wlane;
#pragma unroll 2
    for (int ci = 0; ci < CIN; ++ci) {
      const float* xrow = xp + ((ci * XH + iy) * WP + ixp0) * 8;  // uniform
      const v2f cw0 = *(const v2f*)(wk + ci * (NA * NC));
      const v2f cw1 = *(const v2f*)(wk + 2 * (CIN * NA * NC) + ci * (NA * NC));
      v2f cw2 = (v2f){0.f, 0.f};
      if (use_t2) cw2 = *(const v2f*)(wk + 4 * (CIN * NA * NC) + ci * (NA * NC));
#pragma unroll
      for (int ir = 0; ir < 6; ++ir) {
        if (ir == 5 && !use_t2) continue;              // odd parity: ir<=4
        const float4 xlo = *(const float4*)(xrow + ir * 8);      // uniform
        const float4 xhi = *(const float4*)(xrow + ir * 8 + 4);
        const float xv[8] = {xlo.x, xlo.y, xlo.z, xlo.w,
                             xhi.x, xhi.y, xhi.z, xhi.w};
        if (ir <= 3) {                                 // tap t=0, j=ir
#pragma unroll
          for (int b = 0; b < 8; ++b) {
            const v2f xs = (v2f){xv[b], xv[b]};
            acc[ir][b] = __builtin_elementwise_fma(xs, cw0, acc[ir][b]);
          }
        }
        if (ir >= 1 && ir <= 4) {                      // tap t=1, j=ir-1
#pragma unroll
          for (int b = 0; b < 8; ++b) {
            const v2f xs = (v2f){xv[b], xv[b]};
            acc[ir - 1][b] = __builtin_elementwise_fma(xs, cw1, acc[ir - 1][b]);
          }
        }
        if (ir >= 2 && use_t2) {                       // tap t=2, j=ir-2
#pragma unroll
          for (int b = 0; b < 8; ++b) {
            const v2f xs = (v2f){xv[b], xv[b]};
            acc[ir - 2][b] = __builtin_elementwise_fma(xs, cw2, acc[ir - 2][b]);
          }
        }
      }
    }
  }

  // -------- routing (2 interleaved pairs) --------
  const int R = nroutes[0];
  v2f q0, q1, q2, q3;
  route_pair(acc[0], acc[1], R, q0, q1);
  route_pair(acc[2], acc[3], R, q2, q3);

  // -------- stage results to LDS: [pxi][a*16+c] --------
  const int lbase = a * NC + cg * 2;
  *(v2f*)&lds_out[(pxb    ) * 128 + lbase] = q0;
  *(v2f*)&lds_out[(pxb + 2) * 128 + lbase] = q1;
  *(v2f*)&lds_out[(pxb + 4) * 128 + lbase] = q2;
  *(v2f*)&lds_out[(pxb + 6) * 128 + lbase] = q3;
  __syncthreads();

  // -------- coalesced output: thread -> (row r = a*16+c, half h) --------
  const int t = threadIdx.x;
  const int r = t >> 1, h = t & 1;
  float4 f0, f1;
  f0.x = lds_out[(h * 8 + 0) * 128 + r];
  f0.y = lds_out[(h * 8 + 1) * 128 + r];
  f0.z = lds_out[(h * 8 + 2) * 128 + r];
  f0.w = lds_out[(h * 8 + 3) * 128 + r];
  f1.x = lds_out[(h * 8 + 4) * 128 + r];
  f1.y = lds_out[(h * 8 + 5) * 128 + r];
  f1.z = lds_out[(h * 8 + 6) * 128 + r];
  f1.w = lds_out[(h * 8 + 7) * 128 + r];
  float* op = out + r * (OH * OW) + oy * OW + xg + h * 8;
  *(float4*)op       = f0;
  *(float4*)(op + 4) = f1;
}

extern "C" void kernel_launch(void* const* d_in, const int* in_sizes, int n_in,
                              void* d_out, int out_size, void* d_ws, size_t ws_size,
                              hipStream_t stream) {
  const float* x   = (const float*)d_in[0];
  const float* w   = (const float*)d_in[1];
  const int*   nr  = (const int*)d_in[2];
  float*       out = (float*)d_out;
  float*       xp  = (float*)d_ws;       // needs PADN*4 = 5,013,504 bytes

  pad_x<<<(PADN + 255) / 256, 256, 0, stream>>>(x, xp);
  upcaps_tr7<<<(OH * OW) / 16, 256, 0, stream>>>(xp, w, nr, out);
}

// Round 13
// 140.693 us; speedup vs baseline: 1.8454x; 1.0400x over previous
//
#include <hip/hip_runtime.h>

// UpCaps fused, transposed lanes + packed-fp32 math, load-batched conv.
// lane = a*8 + cg (cg = c/2); each lane holds votes for all 8 batches of its
// (a, c=2cg..2cg+1) as float2 (v2f) -> conv inner loop is v_pk_fma_f32.
// x repacked into d_ws as xp[ci][iy][ixp][b] (padded) so conv x-reads are
// wave-uniform 32B loads, no edge branches.
// R13 delta vs R8: per (ky,ci) iteration, ALL 12 x float4 loads + 3 w loads
// are issued BEFORE the 112-pk-FMA block (single vmcnt wait per iteration
// instead of ~6 interleaved waits -> cycle model says VALU saturates at
// 3 waves/SIMD). unroll 1 on ci keeps xq single-buffered (VGPR ~130 < 168).
// OCCUPANCY LEDGER (measured): (256,3) cap 168 -> 84 VGPR clean 144us (R8);
// (256,4) -> compiler jumps to 64-VGPR bucket + spills (R12, 157us);
// (256,5)/(512,8) -> forced 64/32 bucket, 0.5-1GB spill (R10/R11). Keep (256,3).
// Softmax over b lane-local; squash over a-lanes (xor 8,16,32); logit update
// over cg-lanes (xor 1,2,4). Output via 8KB LDS transpose -> 64B-line stores.
// Shapes: x(8,16,96,96), w(5,5,16,8,16), out(8,16,192,192).
typedef float v2f __attribute__((ext_vector_type(2)));

#define XH 96
#define XW 96
#define CIN 16
#define NA 8
#define NC 16
#define OH 192
#define OW 192
#define WP 102                        // padded width: ix in [-1,100] -> ixp 0..101
#define PADN (CIN * XH * WP * 8)      // 1,253,376 floats

__global__ __launch_bounds__(256) void pad_x(const float* __restrict__ x,
                                             float* __restrict__ xp) {
  int idx = blockIdx.x * 256 + threadIdx.x;
  if (idx >= PADN) return;
  int b   = idx & 7;
  int t   = idx >> 3;
  int ixp = t % WP;
  int t2  = t / WP;
  int iy  = t2 % XH;
  int ci  = t2 / XH;
  int ix  = ixp - 1;
  float v = 0.f;
  if (ix >= 0 && ix < XW)
    v = x[((b * CIN + ci) * XH + iy) * XW + ix];
  xp[idx] = v;
}

// routes two pixels interleaved; va/vb = votes[b] (c-pair) for this lane's
// (a, 2cg..2cg+1). On exit qa/qb hold final squashed preds (c-pair).
__device__ __forceinline__ void route_pair(
    const v2f (&va)[8], const v2f (&vb)[8], int R, v2f& qa, v2f& qb)
{
  float lga[8], lgb[8];
#pragma unroll
  for (int b = 0; b < 8; ++b) { lga[b] = 0.f; lgb[b] = 0.f; }
#pragma unroll 1
  for (int r = 0; r < R; ++r) {
    float sla[8], slb[8];
    if (r == 0) {
#pragma unroll
      for (int b = 0; b < 8; ++b) { sla[b] = 0.125f; slb[b] = 0.125f; }
    } else {
      // softmax over batch: fully lane-local
      float ma = lga[0], mb = lgb[0];
#pragma unroll
      for (int b = 1; b < 8; ++b) { ma = fmaxf(ma, lga[b]); mb = fmaxf(mb, lgb[b]); }
      float sa = 0.f, sb = 0.f;
#pragma unroll
      for (int b = 0; b < 8; ++b) {
        sla[b] = __expf(lga[b] - ma); sa += sla[b];
        slb[b] = __expf(lgb[b] - mb); sb += slb[b];
      }
      const float ira = __builtin_amdgcn_rcpf(sa);   // sa >= 1 > 0
      const float irb = __builtin_amdgcn_rcpf(sb);
#pragma unroll
      for (int b = 0; b < 8; ++b) { sla[b] *= ira; slb[b] *= irb; }
    }

    // preds = sum_b votes * sl : lane-local pk-FMA chain
    qa = (v2f){0.f, 0.f};  qb = (v2f){0.f, 0.f};
#pragma unroll
    for (int b = 0; b < 8; ++b) {
      qa = __builtin_elementwise_fma((v2f){sla[b], sla[b]}, va[b], qa);
      qb = __builtin_elementwise_fma((v2f){slb[b], slb[b]}, vb[b], qb);
    }

    // squash: norm^2 over atoms = reduce over a-lanes (bits 3..5)
    {
      float na0 = qa.x * qa.x, na1 = qa.y * qa.y;
      float nb0 = qb.x * qb.x, nb1 = qb.y * qb.y;
      na0 += __shfl_xor(na0, 8);  na1 += __shfl_xor(na1, 8);
      nb0 += __shfl_xor(nb0, 8);  nb1 += __shfl_xor(nb1, 8);
      na0 += __shfl_xor(na0, 16); na1 += __shfl_xor(na1, 16);
      nb0 += __shfl_xor(nb0, 16); nb1 += __shfl_xor(nb1, 16);
      na0 += __shfl_xor(na0, 32); na1 += __shfl_xor(na1, 32);
      nb0 += __shfl_xor(nb0, 32); nb1 += __shfl_xor(nb1, 32);
      qa.x *= sqrtf(na0) * __builtin_amdgcn_rcpf(1.f + na0);  // sqrt(n)/(1+n)
      qa.y *= sqrtf(na1) * __builtin_amdgcn_rcpf(1.f + na1);
      qb.x *= sqrtf(nb0) * __builtin_amdgcn_rcpf(1.f + nb0);
      qb.y *= sqrtf(nb1) * __builtin_amdgcn_rcpf(1.f + nb1);
    }

    // logits = softmaxed + sum_c votes*preds (reduce over cg-lanes, bits 0..2)
    if (r + 1 < R) {
#pragma unroll
      for (int b = 0; b < 8; ++b) {
        float da = fmaf(va[b].x, qa.x, va[b].y * qa.y);
        float db = fmaf(vb[b].x, qb.x, vb[b].y * qb.y);
        da += __shfl_xor(da, 1);  db += __shfl_xor(db, 1);
        da += __shfl_xor(da, 2);  db += __shfl_xor(db, 2);
        da += __shfl_xor(da, 4);  db += __shfl_xor(db, 4);
        lga[b] = sla[b] + da;     lgb[b] = slb[b] + db;
      }
    }
  }
}

__global__ __launch_bounds__(256, 3) void upcaps_tr8(
    const float* __restrict__ xp,    // padded [ci][iy][ixp][b]
    const float* __restrict__ wts,
    const int* __restrict__ nroutes,
    float* __restrict__ out)
{
  __shared__ float lds_out[16 * 128];   // 8KB: [pxi][a*16+c]

  const int lane = threadIdx.x & 63;
  const int wid  = threadIdx.x >> 6;
  const int tile = blockIdx.x;          // 2304 blocks, 16 px each
  const int oy   = tile / 12;
  const int xg   = (tile - oy * 12) * 16;            // 64B-line aligned
  const int pxb  = (wid & 1) + ((wid >> 1) << 3);    // wave px: pxb + 2j
  const int oxw  = xg + pxb;
  const int a    = lane >> 3;
  const int cg   = lane & 7;
  const int e    = oxw & 1;
  // conv input col: ix = ixb + t + j,  t,j in [0,2]x[0,3]
  const int ixp0 = __builtin_amdgcn_readfirstlane(((oxw - 2 + e) >> 1) + 1);
  const bool use_t2 = (__builtin_amdgcn_readfirstlane(e) == 0);
  const int wlane = a * NC + cg * 2;    // per-lane float offset into w[..][a][c]

  v2f acc[4][8];
#pragma unroll
  for (int j = 0; j < 4; ++j)
#pragma unroll
    for (int b = 0; b < 8; ++b) acc[j][b] = (v2f){0.f, 0.f};

  for (int ky = 0; ky < 5; ++ky) {
    const int py = oy - 2 + ky;
    if (py < 0 || py > 2 * XH - 2 || (py & 1)) continue;   // wave-uniform
    const int iy = py >> 1;
    const float* wk = wts + (ky * 5 + e) * (CIN * NA * NC) + wlane;
#pragma unroll 1
    for (int ci = 0; ci < CIN; ++ci) {
      const float* xrow = xp + ((ci * XH + iy) * WP + ixp0) * 8;  // uniform
      // ---- batch-issue ALL loads for this iteration (single vmcnt wait) ----
      float4 xq[12];                    // 6 cols x {lo,hi}; col 5 unused if odd
#pragma unroll
      for (int k = 0; k < 6; ++k) {
        xq[2 * k]     = *(const float4*)(xrow + k * 8);
        xq[2 * k + 1] = *(const float4*)(xrow + k * 8 + 4);
      }
      const v2f cw0 = *(const v2f*)(wk + ci * (NA * NC));
      const v2f cw1 = *(const v2f*)(wk + 2 * (CIN * NA * NC) + ci * (NA * NC));
      v2f cw2 = (v2f){0.f, 0.f};
      if (use_t2) cw2 = *(const v2f*)(wk + 4 * (CIN * NA * NC) + ci * (NA * NC));
      // ---- FMA block: col ir feeds (tap t, px j) with t + j == ir ----
#pragma unroll
      for (int ir = 0; ir < 6; ++ir) {
        const float xv[8] = {xq[2*ir].x, xq[2*ir].y, xq[2*ir].z, xq[2*ir].w,
                             xq[2*ir+1].x, xq[2*ir+1].y, xq[2*ir+1].z, xq[2*ir+1].w};
        if (ir <= 3) {                                 // tap t=0, j=ir
#pragma unroll
          for (int b = 0; b < 8; ++b) {
            const v2f xs = (v2f){xv[b], xv[b]};
            acc[ir][b] = __builtin_elementwise_fma(xs, cw0, acc[ir][b]);
          }
        }
        if (ir >= 1 && ir <= 4) {                      // tap t=1, j=ir-1
#pragma unroll
          for (int b = 0; b < 8; ++b) {
            const v2f xs = (v2f){xv[b], xv[b]};
            acc[ir - 1][b] = __builtin_elementwise_fma(xs, cw1, acc[ir - 1][b]);
          }
        }
        if (ir >= 2 && use_t2) {                       // tap t=2, j=ir-2
#pragma unroll
          for (int b = 0; b < 8; ++b) {
            const v2f xs = (v2f){xv[b], xv[b]};
            acc[ir - 2][b] = __builtin_elementwise_fma(xs, cw2, acc[ir - 2][b]);
          }
        }
      }
    }
  }

  // -------- routing (2 interleaved pairs) --------
  const int R = nroutes[0];
  v2f q0, q1, q2, q3;
  route_pair(acc[0], acc[1], R, q0, q1);
  route_pair(acc[2], acc[3], R, q2, q3);

  // -------- stage results to LDS: [pxi][a*16+c] --------
  const int lbase = a * NC + cg * 2;
  *(v2f*)&lds_out[(pxb    ) * 128 + lbase] = q0;
  *(v2f*)&lds_out[(pxb + 2) * 128 + lbase] = q1;
  *(v2f*)&lds_out[(pxb + 4) * 128 + lbase] = q2;
  *(v2f*)&lds_out[(pxb + 6) * 128 + lbase] = q3;
  __syncthreads();

  // -------- coalesced output: thread -> (row r = a*16+c, half h) --------
  const int t = threadIdx.x;
  const int r = t >> 1, h = t & 1;
  float4 f0, f1;
  f0.x = lds_out[(h * 8 + 0) * 128 + r];
  f0.y = lds_out[(h * 8 + 1) * 128 + r];
  f0.z = lds_out[(h * 8 + 2) * 128 + r];
  f0.w = lds_out[(h * 8 + 3) * 128 + r];
  f1.x = lds_out[(h * 8 + 4) * 128 + r];
  f1.y = lds_out[(h * 8 + 5) * 128 + r];
  f1.z = lds_out[(h * 8 + 6) * 128 + r];
  f1.w = lds_out[(h * 8 + 7) * 128 + r];
  float* op = out + r * (OH * OW) + oy * OW + xg + h * 8;
  *(float4*)op       = f0;
  *(float4*)(op + 4) = f1;
}

extern "C" void kernel_launch(void* const* d_in, const int* in_sizes, int n_in,
                              void* d_out, int out_size, void* d_ws, size_t ws_size,
                              hipStream_t stream) {
  const float* x   = (const float*)d_in[0];
  const float* w   = (const float*)d_in[1];
  const int*   nr  = (const int*)d_in[2];
  float*       out = (float*)d_out;
  float*       xp  = (float*)d_ws;       // needs PADN*4 = 5,013,504 bytes

  pad_x<<<(PADN + 255) / 256, 256, 0, stream>>>(x, xp);
  upcaps_tr8<<<(OH * OW) / 16, 256, 0, stream>>>(xp, w, nr, out);
}

// Round 14
// 135.971 us; speedup vs baseline: 1.9094x; 1.0347x over previous
//
#include <hip/hip_runtime.h>

// UpCaps fused, transposed lanes, b-pair-packed conv (splat on weights).
// lane = a*8 + cg (cg = c/2). Conv accumulators are packed over BATCH PAIRS
// (b, b+4): acc0/acc1[px][bp] v2f, fed by x register pairs (xp stored
// b-interleaved: b0,b4,b1,b5,b2,b6,b3,b7) and weight-scalar splats cw.{x,y}
// which are LOOP-INVARIANT per (ky,ci) -> 6 hoisted splat movs/iter instead
// of ~112 per-FMA x-splats (R8/R13's hidden cost; pk gain was eaten by movs).
// Routing (unchanged, proven): repack acc into va[8] (c-pair per b);
// softmax over b lane-local; squash over a-lanes (xor 8,16,32); logit update
// over cg-lanes (xor 1,2,4). Output via 8KB LDS transpose -> 64B-line stores.
// OCCUPANCY LEDGER (measured): (256,3) cap 168 -> 84 VGPR clean (R8/R13);
// (256,4) -> compiler jumps to 64-bucket + spills (R12); (256,5)/(512,8) ->
// forced low bucket, 0.5-1GB spill (R10/R11). Keep (256,3).
// Shapes: x(8,16,96,96), w(5,5,16,8,16), out(8,16,192,192).
typedef float v2f __attribute__((ext_vector_type(2)));

#define XH 96
#define XW 96
#define CIN 16
#define NA 8
#define NC 16
#define OH 192
#define OW 192
#define WP 102                        // padded width: ix in [-1,100] -> ixp 0..101
#define PADN (CIN * XH * WP * 8)      // 1,253,376 floats

__global__ __launch_bounds__(256) void pad_x(const float* __restrict__ x,
                                             float* __restrict__ xp) {
  int idx = blockIdx.x * 256 + threadIdx.x;
  if (idx >= PADN) return;
  int pos = idx & 7;                    // b-interleaved: pos = 2*bp + h
  int b   = (pos >> 1) + ((pos & 1) << 2);   // b = bp + 4h
  int t   = idx >> 3;
  int ixp = t % WP;
  int t2  = t / WP;
  int iy  = t2 % XH;
  int ci  = t2 / XH;
  int ix  = ixp - 1;
  float v = 0.f;
  if (ix >= 0 && ix < XW)
    v = x[((b * CIN + ci) * XH + iy) * XW + ix];
  xp[idx] = v;
}

// routes two pixels interleaved; va/vb = votes[b] (c-pair) for this lane's
// (a, 2cg..2cg+1). On exit qa/qb hold final squashed preds (c-pair).
__device__ __forceinline__ void route_pair(
    const v2f (&va)[8], const v2f (&vb)[8], int R, v2f& qa, v2f& qb)
{
  float lga[8], lgb[8];
#pragma unroll
  for (int b = 0; b < 8; ++b) { lga[b] = 0.f; lgb[b] = 0.f; }
#pragma unroll 1
  for (int r = 0; r < R; ++r) {
    float sla[8], slb[8];
    if (r == 0) {
#pragma unroll
      for (int b = 0; b < 8; ++b) { sla[b] = 0.125f; slb[b] = 0.125f; }
    } else {
      // softmax over batch: fully lane-local
      float ma = lga[0], mb = lgb[0];
#pragma unroll
      for (int b = 1; b < 8; ++b) { ma = fmaxf(ma, lga[b]); mb = fmaxf(mb, lgb[b]); }
      float sa = 0.f, sb = 0.f;
#pragma unroll
      for (int b = 0; b < 8; ++b) {
        sla[b] = __expf(lga[b] - ma); sa += sla[b];
        slb[b] = __expf(lgb[b] - mb); sb += slb[b];
      }
      const float ira = __builtin_amdgcn_rcpf(sa);   // sa >= 1 > 0
      const float irb = __builtin_amdgcn_rcpf(sb);
#pragma unroll
      for (int b = 0; b < 8; ++b) { sla[b] *= ira; slb[b] *= irb; }
    }

    // preds = sum_b votes * sl : lane-local pk-FMA chain
    qa = (v2f){0.f, 0.f};  qb = (v2f){0.f, 0.f};
#pragma unroll
    for (int b = 0; b < 8; ++b) {
      qa = __builtin_elementwise_fma((v2f){sla[b], sla[b]}, va[b], qa);
      qb = __builtin_elementwise_fma((v2f){slb[b], slb[b]}, vb[b], qb);
    }

    // squash: norm^2 over atoms = reduce over a-lanes (bits 3..5)
    {
      float na0 = qa.x * qa.x, na1 = qa.y * qa.y;
      float nb0 = qb.x * qb.x, nb1 = qb.y * qb.y;
      na0 += __shfl_xor(na0, 8);  na1 += __shfl_xor(na1, 8);
      nb0 += __shfl_xor(nb0, 8);  nb1 += __shfl_xor(nb1, 8);
      na0 += __shfl_xor(na0, 16); na1 += __shfl_xor(na1, 16);
      nb0 += __shfl_xor(nb0, 16); nb1 += __shfl_xor(nb1, 16);
      na0 += __shfl_xor(na0, 32); na1 += __shfl_xor(na1, 32);
      nb0 += __shfl_xor(nb0, 32); nb1 += __shfl_xor(nb1, 32);
      qa.x *= sqrtf(na0) * __builtin_amdgcn_rcpf(1.f + na0);  // sqrt(n)/(1+n)
      qa.y *= sqrtf(na1) * __builtin_amdgcn_rcpf(1.f + na1);
      qb.x *= sqrtf(nb0) * __builtin_amdgcn_rcpf(1.f + nb0);
      qb.y *= sqrtf(nb1) * __builtin_amdgcn_rcpf(1.f + nb1);
    }

    // logits = softmaxed + sum_c votes*preds (reduce over cg-lanes, bits 0..2)
    if (r + 1 < R) {
#pragma unroll
      for (int b = 0; b < 8; ++b) {
        float da = fmaf(va[b].x, qa.x, va[b].y * qa.y);
        float db = fmaf(vb[b].x, qb.x, vb[b].y * qb.y);
        da += __shfl_xor(da, 1);  db += __shfl_xor(db, 1);
        da += __shfl_xor(da, 2);  db += __shfl_xor(db, 2);
        da += __shfl_xor(da, 4);  db += __shfl_xor(db, 4);
        lga[b] = sla[b] + da;     lgb[b] = slb[b] + db;
      }
    }
  }
}

__global__ __launch_bounds__(256, 3) void upcaps_tr9(
    const float* __restrict__ xp,    // padded [ci][iy][ixp][b-interleaved]
    const float* __restrict__ wts,
    const int* __restrict__ nroutes,
    float* __restrict__ out)
{
  __shared__ float lds_out[16 * 128];   // 8KB: [pxi][a*16+c]

  const int lane = threadIdx.x & 63;
  const int wid  = threadIdx.x >> 6;
  const int tile = blockIdx.x;          // 2304 blocks, 16 px each
  const int oy   = tile / 12;
  const int xg   = (tile - oy * 12) * 16;            // 64B-line aligned
  const int pxb  = (wid & 1) + ((wid >> 1) << 3);    // wave px: pxb + 2j
  const int oxw  = xg + pxb;
  const int a    = lane >> 3;
  const int cg   = lane & 7;
  const int e    = oxw & 1;
  // conv input col: ix = ixb + t + j,  t,j in [0,2]x[0,3]
  const int ixp0 = __builtin_amdgcn_readfirstlane(((oxw - 2 + e) >> 1) + 1);
  const bool use_t2 = (__builtin_amdgcn_readfirstlane(e) == 0);
  const int wlane = a * NC + cg * 2;    // per-lane float offset into w[..][a][c]

  // acc0 = channel c=2cg, acc1 = c=2cg+1; packed over (bp, bp+4)
  v2f acc0[4][4], acc1[4][4];
#pragma unroll
  for (int j = 0; j < 4; ++j)
#pragma unroll
    for (int bp = 0; bp < 4; ++bp) {
      acc0[j][bp] = (v2f){0.f, 0.f};
      acc1[j][bp] = (v2f){0.f, 0.f};
    }

  for (int ky = 0; ky < 5; ++ky) {
    const int py = oy - 2 + ky;
    if (py < 0 || py > 2 * XH - 2 || (py & 1)) continue;   // wave-uniform
    const int iy = py >> 1;
    const float* wk = wts + (ky * 5 + e) * (CIN * NA * NC) + wlane;
#pragma unroll 1
    for (int ci = 0; ci < CIN; ++ci) {
      const float* xrow = xp + ((ci * XH + iy) * WP + ixp0) * 8;  // uniform
      // x columns as v2f b-pairs: col k -> xq2[4k + bp]
      v2f xq2[24];
#pragma unroll
      for (int k = 0; k < 6; ++k) {
        *(float4*)&xq2[4 * k]     = *(const float4*)(xrow + k * 8);
        *(float4*)&xq2[4 * k + 2] = *(const float4*)(xrow + k * 8 + 4);
      }
      // weight splats: loop-invariant for this (ky,ci) -> 6 movs total
      const v2f cw0 = *(const v2f*)(wk + ci * (NA * NC));
      const v2f cw1 = *(const v2f*)(wk + 2 * (CIN * NA * NC) + ci * (NA * NC));
      v2f cw2 = (v2f){0.f, 0.f};
      if (use_t2) cw2 = *(const v2f*)(wk + 4 * (CIN * NA * NC) + ci * (NA * NC));
      const v2f c0x = (v2f){cw0.x, cw0.x}, c0y = (v2f){cw0.y, cw0.y};
      const v2f c1x = (v2f){cw1.x, cw1.x}, c1y = (v2f){cw1.y, cw1.y};
      const v2f c2x = (v2f){cw2.x, cw2.x}, c2y = (v2f){cw2.y, cw2.y};
      // col ir feeds (tap t, px j) with t + j == ir
#pragma unroll
      for (int ir = 0; ir < 6; ++ir) {
        if (ir == 5 && !use_t2) continue;              // odd parity: ir<=4
        if (ir <= 3) {                                 // tap t=0, j=ir
#pragma unroll
          for (int bp = 0; bp < 4; ++bp) {
            const v2f xv = xq2[4 * ir + bp];
            acc0[ir][bp] = __builtin_elementwise_fma(xv, c0x, acc0[ir][bp]);
            acc1[ir][bp] = __builtin_elementwise_fma(xv, c0y, acc1[ir][bp]);
          }
        }
        if (ir >= 1 && ir <= 4) {                      // tap t=1, j=ir-1
#pragma unroll
          for (int bp = 0; bp < 4; ++bp) {
            const v2f xv = xq2[4 * ir + bp];
            acc0[ir-1][bp] = __builtin_elementwise_fma(xv, c1x, acc0[ir-1][bp]);
            acc1[ir-1][bp] = __builtin_elementwise_fma(xv, c1y, acc1[ir-1][bp]);
          }
        }
        if (ir >= 2 && use_t2) {                       // tap t=2, j=ir-2
#pragma unroll
          for (int bp = 0; bp < 4; ++bp) {
            const v2f xv = xq2[4 * ir + bp];
            acc0[ir-2][bp] = __builtin_elementwise_fma(xv, c2x, acc0[ir-2][bp]);
            acc1[ir-2][bp] = __builtin_elementwise_fma(xv, c2y, acc1[ir-2][bp]);
          }
        }
      }
    }
  }

  // -------- repack to routing layout: va[b] = (c0,c1) votes --------
  const int R = nroutes[0];
  v2f q0, q1, q2, q3;
  {
    v2f va[8], vb[8];
#pragma unroll
    for (int bp = 0; bp < 4; ++bp) {
      va[bp]     = (v2f){acc0[0][bp].x, acc1[0][bp].x};   // b = bp
      va[bp + 4] = (v2f){acc0[0][bp].y, acc1[0][bp].y};   // b = bp+4
      vb[bp]     = (v2f){acc0[1][bp].x, acc1[1][bp].x};
      vb[bp + 4] = (v2f){acc0[1][bp].y, acc1[1][bp].y};
    }
    route_pair(va, vb, R, q0, q1);
  }
  {
    v2f va[8], vb[8];
#pragma unroll
    for (int bp = 0; bp < 4; ++bp) {
      va[bp]     = (v2f){acc0[2][bp].x, acc1[2][bp].x};
      va[bp + 4] = (v2f){acc0[2][bp].y, acc1[2][bp].y};
      vb[bp]     = (v2f){acc0[3][bp].x, acc1[3][bp].x};
      vb[bp + 4] = (v2f){acc0[3][bp].y, acc1[3][bp].y};
    }
    route_pair(va, vb, R, q2, q3);
  }

  // -------- stage results to LDS: [pxi][a*16+c] --------
  const int lbase = a * NC + cg * 2;
  *(v2f*)&lds_out[(pxb    ) * 128 + lbase] = q0;
  *(v2f*)&lds_out[(pxb + 2) * 128 + lbase] = q1;
  *(v2f*)&lds_out[(pxb + 4) * 128 + lbase] = q2;
  *(v2f*)&lds_out[(pxb + 6) * 128 + lbase] = q3;
  __syncthreads();

  // -------- coalesced output: thread -> (row r = a*16+c, half h) --------
  const int t = threadIdx.x;
  const int r = t >> 1, h = t & 1;
  float4 f0, f1;
  f0.x = lds_out[(h * 8 + 0) * 128 + r];
  f0.y = lds_out[(h * 8 + 1) * 128 + r];
  f0.z = lds_out[(h * 8 + 2) * 128 + r];
  f0.w = lds_out[(h * 8 + 3) * 128 + r];
  f1.x = lds_out[(h * 8 + 4) * 128 + r];
  f1.y = lds_out[(h * 8 + 5) * 128 + r];
  f1.z = lds_out[(h * 8 + 6) * 128 + r];
  f1.w = lds_out[(h * 8 + 7) * 128 + r];
  float* op = out + r * (OH * OW) + oy * OW + xg + h * 8;
  *(float4*)op       = f0;
  *(float4*)(op + 4) = f1;
}

extern "C" void kernel_launch(void* const* d_in, const int* in_sizes, int n_in,
                              void* d_out, int out_size, void* d_ws, size_t ws_size,
                              hipStream_t stream) {
  const float* x   = (const float*)d_in[0];
  const float* w   = (const float*)d_in[1];
  const int*   nr  = (const int*)d_in[2];
  float*       out = (float*)d_out;
  float*       xp  = (float*)d_ws;       // needs PADN*4 = 5,013,504 bytes

  pad_x<<<(PADN + 255) / 256, 256, 0, stream>>>(x, xp);
  upcaps_tr9<<<(OH * OW) / 16, 256, 0, stream>>>(xp, w, nr, out);
}